// Round 8
// baseline (329.003 us; speedup 1.0000x reference)
//
#include <hip/hip_runtime.h>

#define M_DIM 8192
#define N_DIM 4096
#define K_DIM 4096

typedef int   i32x4  __attribute__((ext_vector_type(4)));
typedef int   i32x8  __attribute__((ext_vector_type(8)));
typedef float f32x16 __attribute__((ext_vector_type(16)));

// Bit-exact replica of reference _cast_e4m3 (round-half-even, subnormals, sat 448)
__device__ __forceinline__ float cast_e4m3(float v) {
    float a = fminf(fabsf(v), 448.0f);
    float am = fmaxf(a, 0x1p-9f);
    int e = (int)((__float_as_uint(am) >> 23) & 0xFFu) - 127;
    e = (e < -6) ? -6 : e;
    float step = __uint_as_float((unsigned)(e - 3 + 127) << 23);
    float q = rintf(a / step) * step;
    q = fminf(q, 448.0f);
    return (v < 0.0f) ? -q : q;
}

// Exact e4m3 byte encoding of an exactly-representable value q (from cast_e4m3)
__device__ __forceinline__ unsigned char enc_e4m3(float q) {
    unsigned u = __float_as_uint(q);
    unsigned s = (u >> 24) & 0x80u;
    float a = fabsf(q);
    if (a == 0.0f) return (unsigned char)s;
    int fe = (int)((u >> 23) & 0xFFu) - 127;
    if (fe < -6) return (unsigned char)(s | (unsigned)(a * 512.0f));   // subnormal, exact
    return (unsigned char)(s | ((unsigned)(fe + 7) << 3) | ((u >> 20) & 7u));
}

// x: per-row 1x128 blocks -> fp8 bytes + f32 scale per (row, kb)
__global__ __launch_bounds__(256) void quant_x(const float* __restrict__ X,
                                               unsigned char* __restrict__ X8,
                                               float* __restrict__ SX) {
    const int g = threadIdx.x >> 5;
    const int l = threadIdx.x & 31;
    const long rb = (long)blockIdx.x * 8 + g;
    const int row = (int)(rb >> 5);
    const int kb = (int)(rb & 31);
    const size_t base = (size_t)row * K_DIM + kb * 128 + l * 4;
    const float4 v = *(const float4*)&X[base];
    float amax = fmaxf(fmaxf(fabsf(v.x), fabsf(v.y)), fmaxf(fabsf(v.z), fabsf(v.w)));
    #pragma unroll
    for (int m = 16; m >= 1; m >>= 1)
        amax = fmaxf(amax, __shfl_xor(amax, m));
    const float scale = fmaxf(amax, 1e-12f) / 448.0f;
    uchar4 o;
    o.x = enc_e4m3(cast_e4m3(v.x / scale));
    o.y = enc_e4m3(cast_e4m3(v.y / scale));
    o.z = enc_e4m3(cast_e4m3(v.z / scale));
    o.w = enc_e4m3(cast_e4m3(v.w / scale));
    *(uchar4*)&X8[base] = o;
    if (l == 0) SX[row * 32 + kb] = scale;
}

// w: 128x128 tiles -> fp8 bytes + f32 scale per tile
__global__ __launch_bounds__(256) void quant_w(const float* __restrict__ W,
                                               unsigned char* __restrict__ W8,
                                               float* __restrict__ SW) {
    const int tile = blockIdx.x;
    const int tr = tile >> 5;
    const int tc = tile & 31;
    const int t = threadIdx.x;
    const int c4 = (t & 31) * 4;
    const float* base = W + (size_t)(tr * 128) * K_DIM + tc * 128;

    float4 v[16];
    float amax = 0.0f;
    #pragma unroll
    for (int p = 0; p < 16; ++p) {
        const int r = p * 8 + (t >> 5);
        v[p] = *(const float4*)&base[(size_t)r * K_DIM + c4];
        amax = fmaxf(amax, fmaxf(fmaxf(fabsf(v[p].x), fabsf(v[p].y)),
                                 fmaxf(fabsf(v[p].z), fabsf(v[p].w))));
    }
    #pragma unroll
    for (int m = 32; m >= 1; m >>= 1)
        amax = fmaxf(amax, __shfl_xor(amax, m));
    __shared__ float red[4];
    if ((t & 63) == 0) red[t >> 6] = amax;
    __syncthreads();
    const float am4 = fmaxf(fmaxf(red[0], red[1]), fmaxf(red[2], red[3]));
    const float scale = fmaxf(am4, 1e-12f) / 448.0f;

    unsigned char* out = W8 + (size_t)(tr * 128) * K_DIM + tc * 128;
    #pragma unroll
    for (int p = 0; p < 16; ++p) {
        const int r = p * 8 + (t >> 5);
        uchar4 o;
        o.x = enc_e4m3(cast_e4m3(v[p].x / scale));
        o.y = enc_e4m3(cast_e4m3(v[p].y / scale));
        o.z = enc_e4m3(cast_e4m3(v[p].z / scale));
        o.w = enc_e4m3(cast_e4m3(v[p].w / scale));
        *(uchar4*)&out[(size_t)r * K_DIM + c4] = o;
    }
    if (t == 0) SW[tr * 32 + tc] = scale;
}

#define GLOAD16(g, l)                                                          \
    __builtin_amdgcn_global_load_lds(                                          \
        (const __attribute__((address_space(1))) void*)(g),                    \
        (__attribute__((address_space(3))) void*)(l), 16, 0, 0)

// =============== fp8 blockwise GEMM: out[t,o] = sum_kb sx*sw*(x8 . w8) =======
// Transposed: A-operand = W8 rows (o), B-operand = X8 rows (t). 256x256 tile,
// K-step 64 bytes; mfma_scale_f32_32x32x64_f8f6f4 with scale=1.0 (0x7F e8m0)
// gives the EXACT fp8 dot; f32 scales applied on the VALU per frag.
// LDS (131072 B): W rings 0/16K/32K, X rings 48K/64K/80K, sx 96K..128K.
// 3-ring, stage 2 steps ahead. Per step: 5 VMEM events {sw(1), W(2), X(2)};
// VMC(5) at step end drains the (u+1) group (issued 1 step ~1500cy earlier)
// and leaves the (u+2) group in flight. Reads (16 DS) same-phase + LGKM(0)
// + sched_barrier (rule 18). Swizzle for 64B rows: granule ^= (row>>1)&3 on
// both stage-source and read (8 consecutive-row lanes -> 8 distinct
// bank-quads; same derivation class as the R5-verified conflict-free XOR).
// Stage-over-read: stage targets ring (u-1)%3 whose reads drained at
// step u-1's LGKM(0), >=1 barrier earlier.

#define BARRIER() __builtin_amdgcn_s_barrier()
#define FENCE()  asm volatile("" ::: "memory")
#define LGKM0()  do { asm volatile("s_waitcnt lgkmcnt(0)" ::: "memory");       \
                      __builtin_amdgcn_sched_barrier(0); } while (0)
#define VMC(n)   asm volatile("s_waitcnt vmcnt(" #n ")" ::: "memory")
#define PRIO1()  __builtin_amdgcn_s_setprio(1)
#define PRIO0()  __builtin_amdgcn_s_setprio(0)

#define MF(va, vb) __builtin_amdgcn_mfma_scale_f32_32x32x64_f8f6f4(            \
                       (va), (vb), zero16, 0, 0, 0, 0x7F, 0, 0x7F)

#define STG(G, rowbase, kt, ringb, ht) do {                                    \
    const unsigned char* _s = (G) +                                            \
        (size_t)((rowbase) + (ht) * 128 + w * 16 + (lane >> 2)) * K_DIM +      \
        (kt) * 64 + srcg;                                                      \
    GLOAD16(_s, (char*)lds + (ringb) + (ht) * 8192 + w * 1024);                \
} while (0)

// read one 8x i32 fragment: 32 k-bytes of row (rowbase + lane&31)
#define LDF(dst, ringb, rowbase) do {                                          \
    const int _r = (rowbase) + (lane & 31);                                    \
    const int _a0 = (ringb) + _r * 64 + (hkb ^ rsw);                           \
    i32x4 _lo = *(const i32x4*)(ldsb + _a0);                                   \
    i32x4 _hi = *(const i32x4*)(ldsb + (_a0 ^ 16));                            \
    dst[0] = _lo[0]; dst[1] = _lo[1]; dst[2] = _lo[2]; dst[3] = _lo[3];        \
    dst[4] = _hi[0]; dst[5] = _hi[1]; dst[6] = _hi[2]; dst[7] = _hi[3];        \
} while (0)

#define RW0B 0
#define RW1B 16384
#define RW2B 32768
#define RX0B 49152
#define RX1B 65536
#define RX2B 81920
#define SXOFF 98304

__global__ __launch_bounds__(512, 2) void gemm256(const unsigned char* __restrict__ W8,
                                                  const unsigned char* __restrict__ X8,
                                                  const float* __restrict__ SX,
                                                  const float* __restrict__ SW,
                                                  const float* __restrict__ bias,
                                                  float* __restrict__ C) {
    __shared__ __align__(16) unsigned char lds[131072];
    const char* ldsb = (const char*)lds;

    const int t = threadIdx.x;
    const int lane = t & 63;
    const int w = t >> 6;                  // 0..7
    const int wm = w >> 1, wn = w & 1;     // 4 (o-rows) x 2 (t-cols); wave = 64 o x 128 t

    int bid = blockIdx.x;
    bid = (bid & 7) * 64 + (bid >> 3);     // 512 blocks, bijective XCD swizzle
    const int bw = bid >> 5;               // 0..15  N-block (W rows, o)
    const int bx = bid & 31;               // 0..31  M-block (X rows, t)
    const size_t brow = (size_t)bw * 256;  // o base
    const size_t bcol = (size_t)bx * 256;  // t base

    // stage-side: row = w*16 + (lane>>2), granule = lane&3; source granule inverse-swizzled
    const int srcg = (((lane & 3) ^ ((lane >> 3) & 3)) << 4);
    // read-side
    const int hkb = 32 * (lane >> 5);               // k-group byte base
    const int rsw = ((lane >> 1) & 3) << 4;         // granule ^= (row>>1)&3
    const int obw = bw * 2 + (wm >> 1);             // wave's W 128-row block

    f32x16 acc00 = {}, acc01 = {}, acc02 = {}, acc03 = {};
    f32x16 acc10 = {}, acc11 = {}, acc12 = {}, acc13 = {};
    const f32x16 zero16 = {};
    i32x8 a0, a1, b0, b1, b2, b3;
    f32x16 p0, p1;

    // ---- prologue ----
    // sx fill: sx_lds[kb][tl] = SX[(bcol+tl)*32 + kb]   (32 KB)
    for (int it = 0; it < 16; ++it) {
        const int idx = it * 512 + t;
        const int tl = idx >> 5, kb = idx & 31;
        const float sv = SX[(bcol + tl) * 32 + kb];
        *(float*)(lds + SXOFF + kb * 1024 + tl * 4) = sv;
    }
    float swn = SW[obw * 32 + 0];
    STG(W8, brow, 0, RW0B, 0); STG(W8, brow, 0, RW0B, 1);
    STG(X8, bcol, 0, RX0B, 0); STG(X8, bcol, 0, RX0B, 1);
    STG(W8, brow, 1, RW1B, 0); STG(W8, brow, 1, RW1B, 1);
    STG(X8, bcol, 1, RX1B, 0); STG(X8, bcol, 1, RX1B, 1);
    VMC(4);                    // drain sw + ring0, leave ring1's 4
    asm volatile("s_waitcnt lgkmcnt(0)" ::: "memory");   // sx-fill writes done
    BARRIER(); FENCE();

    int rw0 = RW0B, rw1 = RW1B, rw2 = RW2B;
    int rx0 = RX0B, rx1 = RX1B, rx2 = RX2B;

    for (int u = 0; u < 64; ++u) {
        const int kt = (u + 2 > 63) ? 63 : u + 2;
        const int kb = u >> 1;
        const int kbn = ((u + 1 > 63) ? 63 : u + 1) >> 1;
        const float swc = swn;
        swn = SW[obw * 32 + kbn];                       // 1 counted VMEM
        STG(W8, brow, kt, rw2, 0); STG(W8, brow, kt, rw2, 1);
        STG(X8, bcol, kt, rx2, 0); STG(X8, bcol, kt, rx2, 1);

        LDF(a0, rw0, wm * 64);
        LDF(a1, rw0, wm * 64 + 32);
        LDF(b0, rx0, wn * 128);
        LDF(b1, rx0, wn * 128 + 32);
        LDF(b2, rx0, wn * 128 + 64);
        LDF(b3, rx0, wn * 128 + 96);
        const int sxb = SXOFF + kb * 1024 + (wn * 128 + (lane & 31)) * 4;
        const float sx0 = *(const float*)(ldsb + sxb);
        const float sx1 = *(const float*)(ldsb + sxb + 128);
        const float sx2 = *(const float*)(ldsb + sxb + 256);
        const float sx3 = *(const float*)(ldsb + sxb + 384);
        LGKM0();

        const float s0 = swc * sx0, s1 = swc * sx1, s2 = swc * sx2, s3 = swc * sx3;
        PRIO1();
        p0 = MF(a0, b0); p1 = MF(a1, b0);
        acc00 += p0 * s0; p0 = MF(a0, b1);
        acc10 += p1 * s0; p1 = MF(a1, b1);
        acc01 += p0 * s1; p0 = MF(a0, b2);
        acc11 += p1 * s1; p1 = MF(a1, b2);
        acc02 += p0 * s2; p0 = MF(a0, b3);
        acc12 += p1 * s2; p1 = MF(a1, b3);
        acc03 += p0 * s3;
        acc13 += p1 * s3;
        PRIO0();

        VMC(5);                                         // leave (u+2) group + swn
        BARRIER(); FENCE();
        int tmp = rw0; rw0 = rw1; rw1 = rw2; rw2 = tmp;
        tmp = rx0; rx0 = rx1; rx1 = rx2; rx2 = tmp;
    }
    VMC(0);

    // C write: o = brow + wm*64 + i*32 + 8g + 4*(lane>>5) + m (m=0..3, float4)
    //          t = bcol + wn*128 + j*32 + (lane&31)
    const int hi4 = (lane >> 5) * 4;
    #pragma unroll
    for (int i = 0; i < 2; ++i) {
        #pragma unroll
        for (int g = 0; g < 4; ++g) {
            const size_t o0 = brow + wm * 64 + i * 32 + 8 * g + hi4;
            const float4 bv = *(const float4*)&bias[o0];
            #pragma unroll
            for (int j = 0; j < 4; ++j) {
                const f32x16* ap =
                    (i == 0) ? (j == 0 ? &acc00 : j == 1 ? &acc01 : j == 2 ? &acc02 : &acc03)
                             : (j == 0 ? &acc10 : j == 1 ? &acc11 : j == 2 ? &acc12 : &acc13);
                const size_t tt = bcol + wn * 128 + j * 32 + (lane & 31);
                float4 val;
                val.x = (*ap)[4 * g + 0] + bv.x;
                val.y = (*ap)[4 * g + 1] + bv.y;
                val.z = (*ap)[4 * g + 2] + bv.z;
                val.w = (*ap)[4 * g + 3] + bv.w;
                *(float4*)&C[tt * (size_t)N_DIM + o0] = val;
            }
        }
    }
}

extern "C" void kernel_launch(void* const* d_in, const int* in_sizes, int n_in,
                              void* d_out, int out_size, void* d_ws, size_t ws_size,
                              hipStream_t stream) {
    const float* x = (const float*)d_in[0];
    const float* wt = (const float*)d_in[1];
    const float* bias = (const float*)d_in[2];
    float* out = (float*)d_out;

    unsigned char* x8 = (unsigned char*)d_ws;                         // 32 MB
    unsigned char* w8 = x8 + (size_t)M_DIM * K_DIM;                   // 16 MB
    float* sx = (float*)(w8 + (size_t)N_DIM * K_DIM);                 // 1 MB
    float* sw = sx + (size_t)M_DIM * 32;                              // 4 KB

    quant_x<<<(M_DIM * (K_DIM / 128)) / 8, 256, 0, stream>>>(x, x8, sx);
    quant_w<<<(N_DIM / 128) * (K_DIM / 128), 256, 0, stream>>>(wt, w8, sw);
    gemm256<<<(M_DIM / 256) * (N_DIM / 256), 512, 0, stream>>>(w8, x8, sx, sw, bias, out);
}

// Round 9
// 304.261 us; speedup vs baseline: 1.0813x; 1.0813x over previous
//
#include <hip/hip_runtime.h>

#define M_DIM 8192
#define N_DIM 4096
#define K_DIM 4096

typedef __bf16 bf16x8 __attribute__((ext_vector_type(8)));
typedef float f32x4 __attribute__((ext_vector_type(4)));

// bf16 round-to-nearest-even from fp32 (no NaN in this problem)
__device__ __forceinline__ unsigned short f2bf(float f) {
    unsigned u = __float_as_uint(f);
    u += 0x7FFFu + ((u >> 16) & 1u);
    return (unsigned short)(u >> 16);
}

// Bit-exact replica of reference _cast_e4m3 (round-half-even, subnormals, sat 448)
__device__ __forceinline__ float cast_e4m3(float v) {
    float a = fminf(fabsf(v), 448.0f);
    float am = fmaxf(a, 0x1p-9f);
    int e = (int)((__float_as_uint(am) >> 23) & 0xFFu) - 127;   // floor(log2(am)), exact
    e = (e < -6) ? -6 : e;
    float step = __uint_as_float((unsigned)(e - 3 + 127) << 23); // 2^(e-3)
    float q = rintf(a / step) * step;                            // a/step exact, RNE tie
    q = fminf(q, 448.0f);
    return (v < 0.0f) ? -q : q;
}

// x: per-row 1x128 blocks. One 32-lane group per block, 4 floats/lane.
__global__ __launch_bounds__(256) void quant_x(const float* __restrict__ X,
                                               unsigned short* __restrict__ Xq) {
    const int g = threadIdx.x >> 5;
    const int l = threadIdx.x & 31;
    const long rb = (long)blockIdx.x * 8 + g;
    const int row = (int)(rb >> 5);
    const int kb = (int)(rb & 31);
    const size_t base = (size_t)row * K_DIM + kb * 128 + l * 4;
    const float4 v = *(const float4*)&X[base];
    float amax = fmaxf(fmaxf(fabsf(v.x), fabsf(v.y)), fmaxf(fabsf(v.z), fabsf(v.w)));
    #pragma unroll
    for (int m = 16; m >= 1; m >>= 1)
        amax = fmaxf(amax, __shfl_xor(amax, m));
    const float scale = fmaxf(amax, 1e-12f) / 448.0f;
    ushort4 o;
    o.x = f2bf(cast_e4m3(v.x / scale) * scale);
    o.y = f2bf(cast_e4m3(v.y / scale) * scale);
    o.z = f2bf(cast_e4m3(v.z / scale) * scale);
    o.w = f2bf(cast_e4m3(v.w / scale) * scale);
    *(ushort4*)&Xq[base] = o;
}

// w: 128x128 tiles. One 256-thread block per tile; values held in registers.
__global__ __launch_bounds__(256) void quant_w(const float* __restrict__ W,
                                               unsigned short* __restrict__ Wq) {
    const int tile = blockIdx.x;
    const int tr = tile >> 5;
    const int tc = tile & 31;
    const int t = threadIdx.x;
    const int c4 = (t & 31) * 4;
    const float* base = W + (size_t)(tr * 128) * K_DIM + tc * 128;

    float4 v[16];
    float amax = 0.0f;
    #pragma unroll
    for (int p = 0; p < 16; ++p) {
        const int r = p * 8 + (t >> 5);
        v[p] = *(const float4*)&base[(size_t)r * K_DIM + c4];
        amax = fmaxf(amax, fmaxf(fmaxf(fabsf(v[p].x), fabsf(v[p].y)),
                                 fmaxf(fabsf(v[p].z), fabsf(v[p].w))));
    }
    #pragma unroll
    for (int m = 32; m >= 1; m >>= 1)
        amax = fmaxf(amax, __shfl_xor(amax, m));
    __shared__ float red[4];
    if ((t & 63) == 0) red[t >> 6] = amax;
    __syncthreads();
    const float am4 = fmaxf(fmaxf(red[0], red[1]), fmaxf(red[2], red[3]));
    const float scale = fmaxf(am4, 1e-12f) / 448.0f;

    unsigned short* out = Wq + (size_t)(tr * 128) * K_DIM + tc * 128;
    #pragma unroll
    for (int p = 0; p < 16; ++p) {
        const int r = p * 8 + (t >> 5);
        ushort4 o;
        o.x = f2bf(cast_e4m3(v[p].x / scale) * scale);
        o.y = f2bf(cast_e4m3(v[p].y / scale) * scale);
        o.z = f2bf(cast_e4m3(v[p].z / scale) * scale);
        o.w = f2bf(cast_e4m3(v[p].w / scale) * scale);
        *(ushort4*)&out[(size_t)r * K_DIM + c4] = o;
    }
}

#define GLOAD16(g, l)                                                          \
    __builtin_amdgcn_global_load_lds(                                          \
        (const __attribute__((address_space(1))) void*)(g),                    \
        (__attribute__((address_space(3))) void*)(l), 16, 0, 0)

// ============ 256x256 8-phase GEMM, BK=32, 8 waves, 64KB LDS (2 blocks/CU) ====
// R5's proven ledger scaled to BK=32 for 2-blocks/CU occupancy (TLP fills the
// barrier-drain gaps; m114 co-scheduling). LDS element bases: A0E=0, A1E=8192,
// B0E=16384, B1E=24576 (x2B = 64KiB). Even tile -> E bufs (A0E/B0E), odd -> O.
// Stage unit = 1 gload (8KB = 128 rows x 64B). Ledger (tile u @P1-4, u+1 @P5-8):
//   P1:A0(u+1) P2:A1(u+1) P3:B0(u+2) P4:B1(u+2)+vmcnt(2)
//   P5:A0(u+2) P6:A1(u+2) P7:B0(u+3) P8:B1(u+3)+vmcnt(2)
// vmcnt(2) at P4 drains B(u+1),A(u+1) (issued >=2 phases = ~1500cy earlier,
// > HBM 900cy) and leaves B(u+2) in flight; P8 mirrors (drains B(u+2),A(u+2),
// leaves B(u+3)) — same safety proof as R5 with units halved. B-buf reads
// drain at P2's lgkm (stage @P3 >=1 barrier later); A-buf reads at P3's
// (stage @P5). kt clamped to 127: tail stages write dead regions (R6-proven).
// Swizzle for 64B rows (re-derived via the R5-validated 8-lane bank-quad
// method): LDS[row][k16] holds logical granule k16 ^ ((row>>1)&3). 8
// consecutive-row lanes: even rows cover quads {k^0..k^3} (banks 0-15), odd
// rows +4 (banks 16-31) -> 8 distinct quads, conflict-free. Stage: linear
// dest, source granule (t&3)^((t>>3)&3) (row = t>>2 per call; involution).

#define BARRIER() __builtin_amdgcn_s_barrier()
#define LGKM0() asm volatile("s_waitcnt lgkmcnt(0)" ::: "memory")
#define VM2()   asm volatile("s_waitcnt vmcnt(2)" ::: "memory")
#define VM0()   asm volatile("s_waitcnt vmcnt(0)" ::: "memory")
#define PRIO1() __builtin_amdgcn_s_setprio(1)
#define PRIO0() __builtin_amdgcn_s_setprio(0)

// one 8KB stage call: rows ht*128 + t/4, 16B granule t&3 (inverse-swizzled src)
#define STAGE(G, grow0, kt, ebase, ht) do {                                    \
    const int _kt = (kt) > 127 ? 127 : (kt);                                   \
    const unsigned short* _s = (G) +                                           \
        (size_t)((grow0) + (ht) * 128 + (t >> 2)) * K_DIM + _kt * 32 + src_e;  \
    GLOAD16(_s, (char*)lds + (ebase) * 2 + (ht) * 8192 + w * 1024);            \
} while (0)

#define LDA(mh, ebase) do {                                                    \
    _Pragma("unroll") for (int _m = 0; _m < 4; ++_m) {                         \
        const int _row = wm * 128 + (mh) * 64 + _m * 16 + lr;                  \
        a[_m] = *(const bf16x8*)&lds[(ebase) + _row * 32 + rde];               \
    }                                                                          \
} while (0)

#define LDB(nh, dst, ebase) do {                                               \
    _Pragma("unroll") for (int _n = 0; _n < 2; ++_n) {                         \
        const int _row = wn * 64 + (nh) * 32 + _n * 16 + lr;                   \
        dst[_n] = *(const bf16x8*)&lds[(ebase) + _row * 32 + rde];             \
    }                                                                          \
} while (0)

#define MMA(mh, nh, bb) do {                                                   \
    _Pragma("unroll") for (int _m = 0; _m < 4; ++_m)                           \
    _Pragma("unroll") for (int _n = 0; _n < 2; ++_n)                           \
        acc[(mh) * 4 + _m][(nh) * 2 + _n] =                                    \
            __builtin_amdgcn_mfma_f32_16x16x32_bf16(                           \
                a[_m], bb[_n], acc[(mh) * 4 + _m][(nh) * 2 + _n], 0, 0, 0);    \
} while (0)

#define A0E 0
#define A1E 8192
#define B0E 16384
#define B1E 24576

__global__ __launch_bounds__(512, 2) void gemm256(const unsigned short* __restrict__ A,
                                                  const unsigned short* __restrict__ B,
                                                  const float* __restrict__ bias,
                                                  float* __restrict__ C) {
    __shared__ __align__(16) unsigned short lds[32768];   // 64 KiB -> 2 blocks/CU

    const int t = threadIdx.x;
    const int lane = t & 63;
    const int w = t >> 6;                 // 0..7
    const int wm = w >> 2, wn = w & 3;    // 2M x 4N wave grid

    int bid = blockIdx.x;
    bid = (bid & 7) * 64 + (bid >> 3);    // 512 blocks, %8==0 -> bijective
    const int bm = bid >> 4, bn = bid & 15;
    const size_t brow = (size_t)bm * 256, bcol = (size_t)bn * 256;

    // stage-side: per-call row = t>>2, granule = t&3; inverse-swizzled source
    const int src_e = ((lane & 3) ^ ((t >> 3) & 3)) * 8;
    // read-side: row bits 1-2 = lane bits 1-2; k16 granule = lane>>4
    const int lr = lane & 15;
    const int rde = (((lane >> 4) ^ (lane >> 1)) & 3) << 3;   // elements

    f32x4 acc[8][4] = {};
    bf16x8 a[4], b0[2], b1[2];

    // prologue: A(0),B(0) -> E bufs, B(1) -> O B-buf (6 calls);
    // vmcnt(2) drains tile0, leaves B(1) in flight (= steady P1 entry state).
    STAGE(A, brow, 0, A0E, 0); STAGE(A, brow, 0, A0E, 1);
    STAGE(B, bcol, 0, B0E, 0); STAGE(B, bcol, 0, B0E, 1);
    STAGE(B, bcol, 1, B1E, 0); STAGE(B, bcol, 1, B1E, 1);
    VM2(); BARRIER();

    for (int u = 0; u < 128; u += 2) {
        // P1: quad(0,0) of tile u
        LDA(0, A0E); LDB(0, b0, B0E);
        STAGE(A, brow, u + 1, A1E, 0);
        BARRIER(); LGKM0();
        PRIO1(); MMA(0, 0, b0); PRIO0();
        BARRIER();
        // P2: quad(0,1)
        LDB(1, b1, B0E);
        STAGE(A, brow, u + 1, A1E, 1);
        BARRIER(); LGKM0();
        PRIO1(); MMA(0, 1, b1); PRIO0();
        BARRIER();
        // P3: quad(1,1)
        LDA(1, A0E);
        STAGE(B, bcol, u + 2, B0E, 0);
        BARRIER(); LGKM0();
        PRIO1(); MMA(1, 1, b1); PRIO0();
        BARRIER();
        // P4: quad(1,0), K-tile boundary
        STAGE(B, bcol, u + 2, B0E, 1);
        BARRIER();
        PRIO1(); MMA(1, 0, b0); PRIO0();
        VM2();
        BARRIER();
        // P5: quad(0,0) of tile u+1 (O bufs)
        LDA(0, A1E); LDB(0, b0, B1E);
        STAGE(A, brow, u + 2, A0E, 0);
        BARRIER(); LGKM0();
        PRIO1(); MMA(0, 0, b0); PRIO0();
        BARRIER();
        // P6: quad(0,1)
        LDB(1, b1, B1E);
        STAGE(A, brow, u + 2, A0E, 1);
        BARRIER(); LGKM0();
        PRIO1(); MMA(0, 1, b1); PRIO0();
        BARRIER();
        // P7: quad(1,1)
        LDA(1, A1E);
        STAGE(B, bcol, u + 3, B1E, 0);
        BARRIER(); LGKM0();
        PRIO1(); MMA(1, 1, b1); PRIO0();
        BARRIER();
        // P8: quad(1,0), K-tile boundary
        STAGE(B, bcol, u + 3, B1E, 1);
        BARRIER();
        PRIO1(); MMA(1, 0, b0); PRIO0();
        VM2();
        BARRIER();
    }

    VM0();   // drain dead tail stages before endpgm

    // C write: acc[i][j] -> row = wm*128 + i*16 + (lane>>4)*4 + jj, col = wn*64 + j*16 + (lane&15)
    #pragma unroll
    for (int i = 0; i < 8; ++i) {
        const size_t row_base = brow + wm * 128 + i * 16 + (lane >> 4) * 4;
        #pragma unroll
        for (int j = 0; j < 4; ++j) {
            const size_t col = bcol + wn * 64 + j * 16 + lr;
            const float bv = bias[col];
            #pragma unroll
            for (int jj = 0; jj < 4; ++jj)
                C[(row_base + jj) * (size_t)N_DIM + col] = acc[i][j][jj] + bv;
        }
    }
}

extern "C" void kernel_launch(void* const* d_in, const int* in_sizes, int n_in,
                              void* d_out, int out_size, void* d_ws, size_t ws_size,
                              hipStream_t stream) {
    const float* x = (const float*)d_in[0];
    const float* w = (const float*)d_in[1];
    const float* bias = (const float*)d_in[2];
    float* out = (float*)d_out;

    unsigned short* xq = (unsigned short*)d_ws;
    unsigned short* wq = xq + (size_t)M_DIM * K_DIM;

    quant_x<<<(M_DIM * (K_DIM / 128)) / 8, 256, 0, stream>>>(x, xq);
    quant_w<<<(N_DIM / 128) * (K_DIM / 128), 256, 0, stream>>>(w, wq);
    gemm256<<<(M_DIM / 256) * (N_DIM / 256), 512, 0, stream>>>(xq, wq, bias, out);
}